// Round 8
// baseline (103.617 us; speedup 1.0000x reference)
//
#include <hip/hip_runtime.h>
#include <stdint.h>

// N=2048, M=128, D_IN=352, H1=512, D=256, OUT_C=13.  All device tensors FLOAT32.
// Algebra: diff = A[n]-B[m] affine -> fold SharedMLP conv1 into PA2[n,32]/PB2[m,32];
// softmax over m sums to 1 -> att[n,c] = A[n,c] - sum_m wei[n,m,c]*B[m,c].
// Round 8: concurrency round. main_attn c-split (grid 2048x2, atomic fc partials),
// encoders retiled to 32x64 (2x blocks), proj split-K. Latency-bound diagnosis:
// duration was insensitive to instr count; occupancy pinned ~19%.

typedef __attribute__((ext_vector_type(4))) float float4_t;
typedef __attribute__((ext_vector_type(4))) float f32x4;
typedef __attribute__((ext_vector_type(8))) short bf16x8;
typedef __attribute__((ext_vector_type(8))) unsigned short ushort8_t;
typedef __attribute__((ext_vector_type(4))) unsigned short ushort4_t;
typedef unsigned short ushort_t;

__device__ __forceinline__ float b2f(unsigned short u) {
  union { unsigned int i; float f; } v; v.i = ((unsigned int)u) << 16; return v.f;
}
__device__ __forceinline__ unsigned short f2b(float f) {
  union { float f; unsigned int i; } v; v.f = f;
  unsigned int x = v.i;
  return (unsigned short)((x + 0x7FFFu + ((x >> 16) & 1u)) >> 16);
}

// load 8 contiguous elements as bf16, converting if source is f32
template<int ISBF>
__device__ __forceinline__ ushort8_t ld8(const void* base, size_t idx) {
  if constexpr (ISBF) {
    return *(const ushort8_t*)((const ushort_t*)base + idx);
  } else {
    const float* p = (const float*)base + idx;
    float4_t v0 = *(const float4_t*)p;
    float4_t v1 = *(const float4_t*)(p + 4);
    ushort8_t u;
    #pragma unroll
    for (int e = 0; e < 4; ++e) { u[e] = f2b(v0[e]); u[4 + e] = f2b(v1[e]); }
    return u;
  }
}

// ---------- MFMA encoder: Y = relu(g*(X @ W^T + b) + be); 32x64 tile ----------
// 4 waves, wave w owns 16-col slice, 2 m-tiles each.  A and B problems merged via bx.
// B-branch of the f32-out stage also writes Benc^T as bf16 (YBTb[c*128+row]).
template<int XBF, int WBF, int OUT_BF16>
__global__ __launch_bounds__(256) void enc_mfma(
    const void* __restrict__ XA, const void* __restrict__ WA,
    const float* __restrict__ bA, const float* __restrict__ gA, const float* __restrict__ beA,
    void* __restrict__ YA,
    const void* __restrict__ XB, const void* __restrict__ WB,
    const float* __restrict__ bB, const float* __restrict__ gB, const float* __restrict__ beB,
    void* __restrict__ YB, ushort_t* __restrict__ YBTb,
    int J, int K, int nbxA)
{
  __shared__ ushort_t Xs[32][40];
  __shared__ ushort_t Ws[64][40];
  const int bx = blockIdx.x, by = blockIdx.y;
  const void* X; const void* W;
  const float *bb, *gg, *bev; void* Y; int i0, isB;
  if (bx < nbxA) { X = XA; W = WA; bb = bA; gg = gA; bev = beA; Y = YA; i0 = bx * 32; isB = 0; }
  else           { X = XB; W = WB; bb = bB; gg = gB; bev = beB; Y = YB; i0 = (bx - nbxA) * 32; isB = 1; }
  const int j0 = by * 64;
  const int tid = threadIdx.x, w = tid >> 6, lane = tid & 63, lg = lane >> 4, lr = lane & 15;
  const int wr = tid >> 2, wk = (tid & 3) * 8;   // Ws: 64 rows x 4 thr/row x 8 elems
  const int xr = tid >> 2;                        // Xs (tid<128): 32 rows x 4 thr/row

  f32x4 acc[2];
  acc[0] = f32x4{0.f, 0.f, 0.f, 0.f};
  acc[1] = f32x4{0.f, 0.f, 0.f, 0.f};

  ushort8_t wv = ld8<WBF>(W, (size_t)(j0 + wr) * K + wk);
  ushort8_t xv;
  if (tid < 128) xv = ld8<XBF>(X, (size_t)(i0 + xr) * K + wk);
  for (int kt = 0; kt < K; kt += 32) {
    __syncthreads();
    *(ushort8_t*)&Ws[wr][wk] = wv;
    if (tid < 128) *(ushort8_t*)&Xs[xr][wk] = xv;
    __syncthreads();
    if (kt + 32 < K) {
      wv = ld8<WBF>(W, (size_t)(j0 + wr) * K + kt + 32 + wk);
      if (tid < 128) xv = ld8<XBF>(X, (size_t)(i0 + xr) * K + kt + 32 + wk);
    }
    bf16x8 bfrag = *(const bf16x8*)&Ws[w * 16 + lr][lg * 8];
    #pragma unroll
    for (int mt = 0; mt < 2; ++mt) {
      bf16x8 af = *(const bf16x8*)&Xs[mt * 16 + lr][lg * 8];
      acc[mt] = __builtin_amdgcn_mfma_f32_16x16x32_bf16(af, bfrag, acc[mt], 0, 0, 0);
    }
  }
  const int c = j0 + w * 16 + lr;
  const float g = gg[c], bv = bb[c], ev = bev[c];
  #pragma unroll
  for (int mt = 0; mt < 2; ++mt)
    #pragma unroll
    for (int r = 0; r < 4; ++r) {
      const int row = i0 + mt * 16 + 4 * lg + r;
      float t = fmaxf(g * (acc[mt][r] + bv) + ev, 0.f);
      if (OUT_BF16) ((ushort_t*)Y)[(size_t)row * J + c] = f2b(t);
      else {
        ((float*)Y)[(size_t)row * J + c] = t;
        if (isB && YBTb) YBTb[(size_t)c * 128 + row] = f2b(t);
      }
    }
}

// ---------- proj: P = fold(X @ mw1^T); 4 rows/block, split-K-2 ----------
// grid: 512 A-blocks + 32 B-blocks + 9 cvt-blocks (mw2/mw3 -> bf16).
__global__ __launch_bounds__(256) void proj32(
    const float* __restrict__ Aenc, const float* __restrict__ Benc,
    const float* __restrict__ mw1, const float* __restrict__ mb1,
    const float* __restrict__ mg1, const float* __restrict__ mbe1,
    float* __restrict__ PA2, float* __restrict__ PB2, int nbxA,
    const float* __restrict__ mw2, const float* __restrict__ mw3,
    ushort_t* __restrict__ mw2b, ushort_t* __restrict__ mw3b)
{
  __shared__ float ps[4][32];
  const int tid = threadIdx.x, bx = blockIdx.x;
  if (bx >= nbxA + 32) {
    const int g = (bx - nbxA - 32) * 256 + tid;   // 2304 groups of 8
    const float* s; ushort_t* d; int j;
    if (g < 256) { s = mw2; d = mw2b; j = g; }
    else         { s = mw3; d = mw3b; j = g - 256; }
    float4_t v0 = *(const float4_t*)&s[(size_t)j * 8];
    float4_t v1 = *(const float4_t*)&s[(size_t)j * 8 + 4];
    ushort8_t u;
    #pragma unroll
    for (int e = 0; e < 4; ++e) { u[e] = f2b(v0[e]); u[4 + e] = f2b(v1[e]); }
    *(ushort8_t*)&d[(size_t)j * 8] = u;
    return;
  }
  const float* X; float* P; int n0, wb;
  if (bx < nbxA) { X = Aenc; P = PA2; n0 = bx * 4; wb = 1; }
  else           { X = Benc; P = PB2; n0 = (bx - nbxA) * 4; wb = 0; }
  const int k = tid & 31, r = (tid >> 5) & 3, half = tid >> 7;
  const int n = n0 + r;
  const float* xp = &X[(size_t)n * 256 + half * 128];
  const float* wp = &mw1[k * 256 + half * 128];
  float s = 0.f;
  #pragma unroll 8
  for (int q = 0; q < 128; q += 4) {
    float4_t xv = *(const float4_t*)&xp[q];
    float4_t wv = *(const float4_t*)&wp[q];
    #pragma unroll
    for (int e = 0; e < 4; ++e) s = fmaf(xv[e], wv[e], s);
  }
  if (half == 1) ps[r][k] = s;
  __syncthreads();
  if (half == 0) {
    s += ps[r][k];
    P[(size_t)n * 32 + k] = wb ? (mg1[k] * (s + mb1[k]) + mbe1[k]) : (mg1[k] * s);
  }
}

// ---------- fused main kernel: grid (2048 n, 2 c-halves), 4 waves ----------
// MFMA 16x16x32_bf16: A frag m=lane&15,k=(lane>>4)*8+e; B frag c=lane&15,same k;
// C/D col=lane&15,row=(lane>>4)*4+reg.
// Block (n, cb) handles c in [cb*128, cb*128+128); phase1 (full h2) duplicated.
// Softmax: relu'd logits >= 0, shift-invariant -> p = exp2(med3(l,0,80)), no max pass.
// fc: per-block partial over its 128 c -> atomicAdd into memset-zeroed outp.
// LDS 18.4KB h2s; reused post-barrier for attL/part.
__global__ __launch_bounds__(256, 2) void main_attn(
    const float* __restrict__ PA2, const float* __restrict__ PB2,
    const float* __restrict__ A, const ushort_t* __restrict__ BmTb,
    const ushort_t* __restrict__ mw2b, const float* __restrict__ mb2,
    const float* __restrict__ mg2, const float* __restrict__ mbe2,
    const ushort_t* __restrict__ mw3b, const float* __restrict__ mb3,
    const float* __restrict__ mg3, const float* __restrict__ mbe3,
    const float* __restrict__ fcw, const float* __restrict__ fcb,
    float* __restrict__ outp)
{
  __shared__ __align__(16) char smem[18432];
  ushort_t* h2s = (ushort_t*)smem;                   // [128][72]
  float* attL = (float*)smem;                        // [128] (reuses dead h2s)
  float* part = (float*)(smem + 512);                // [208]

  const int tid = threadIdx.x;
  const int w = tid >> 6, lane = tid & 63, lg = lane >> 4, lr = lane & 15;
  const int n = blockIdx.x, cb = blockIdx.y;
  const int cbase = cb * 128;
  const float LOG2E = 1.4426950408889634f;

  // ---- phase1: full h2[m][j] = relu(g2*(h1 @ mw2^T + b2) + be2) -> h2s ----
  {
    f32x4 acc1[2][4];
    #pragma unroll
    for (int mt = 0; mt < 2; ++mt)
      #pragma unroll
      for (int jt = 0; jt < 4; ++jt) acc1[mt][jt] = f32x4{0.f, 0.f, 0.f, 0.f};
    bf16x8 a1[2], b1[4];
    {
      const float* pa = &PA2[(size_t)n * 32 + lg * 8];
      float4_t pa0 = *(const float4_t*)pa;
      float4_t pa1 = *(const float4_t*)(pa + 4);
      #pragma unroll
      for (int mt = 0; mt < 2; ++mt) {
        const int m = w * 32 + mt * 16 + lr;
        const float* pb = &PB2[(size_t)m * 32 + lg * 8];
        float4_t pb0 = *(const float4_t*)pb;
        float4_t pb1 = *(const float4_t*)(pb + 4);
        bf16x8 u;
        #pragma unroll
        for (int e = 0; e < 4; ++e) {
          u[e]     = (short)f2b(fmaxf(pa0[e] - pb0[e], 0.f));
          u[4 + e] = (short)f2b(fmaxf(pa1[e] - pb1[e], 0.f));
        }
        a1[mt] = u;
      }
    }
    #pragma unroll
    for (int jt = 0; jt < 4; ++jt)
      b1[jt] = *(const bf16x8*)&mw2b[(jt * 16 + lr) * 32 + lg * 8];
    #pragma unroll
    for (int mt = 0; mt < 2; ++mt)
      #pragma unroll
      for (int jt = 0; jt < 4; ++jt)
        acc1[mt][jt] = __builtin_amdgcn_mfma_f32_16x16x32_bf16(a1[mt], b1[jt], acc1[mt][jt], 0, 0, 0);
    #pragma unroll
    for (int jt = 0; jt < 4; ++jt) {
      const int j = jt * 16 + lr;
      const float g = mg2[j], bv = mb2[j], ev = mbe2[j];
      #pragma unroll
      for (int mt = 0; mt < 2; ++mt)
        #pragma unroll
        for (int r = 0; r < 4; ++r)
          h2s[(w * 32 + mt * 16 + 4 * lg + r) * 72 + jt * 16 + lr] =
              f2b(fmaxf(g * (acc1[mt][jt][r] + bv) + ev, 0.f));
    }
  }
  __syncthreads();

  // ---- phase2: wave w owns c in cbase + [w*32, w*32+32): 2 ct tiles ----
  f32x4 acc[8][2];
  #pragma unroll
  for (int mt = 0; mt < 8; ++mt) {
    acc[mt][0] = f32x4{0.f, 0.f, 0.f, 0.f};
    acc[mt][1] = f32x4{0.f, 0.f, 0.f, 0.f};
  }
  {
    bf16x8 bfr[2][2];
    #pragma unroll
    for (int q = 0; q < 2; ++q) {
      const int c = cbase + w * 32 + q * 16 + lr;
      bfr[q][0] = *(const bf16x8*)&mw3b[(size_t)c * 64 + lg * 8];
      bfr[q][1] = *(const bf16x8*)&mw3b[(size_t)c * 64 + 32 + lg * 8];
    }
    #pragma unroll
    for (int ks = 0; ks < 2; ++ks) {
      #pragma unroll
      for (int mt = 0; mt < 8; ++mt) {
        bf16x8 af = *(const bf16x8*)&h2s[(mt * 16 + lr) * 72 + ks * 32 + lg * 8];
        acc[mt][0] = __builtin_amdgcn_mfma_f32_16x16x32_bf16(af, bfr[0][ks], acc[mt][0], 0, 0, 0);
        acc[mt][1] = __builtin_amdgcn_mfma_f32_16x16x32_bf16(af, bfr[1][ks], acc[mt][1], 0, 0, 0);
      }
    }
  }

  // ---- single-pass no-max softmax over m; B fragments prefetched per ct ----
  float smv[2], wbv[2];
  #pragma unroll
  for (int q = 0; q < 2; ++q) {
    const int c = cbase + w * 32 + q * 16 + lr;
    const float g = mg3[c], bv = mb3[c], ev = mbe3[c];
    const float gs = g * LOG2E;
    const float cs = (g * bv + ev) * LOG2E;
    ushort4_t bcv[8];
    #pragma unroll
    for (int mt = 0; mt < 8; ++mt)
      bcv[mt] = *(const ushort4_t*)&BmTb[(size_t)c * 128 + mt * 16 + 4 * lg];
    f32x4 sm4 = f32x4{0.f, 0.f, 0.f, 0.f};
    f32x4 wb4 = f32x4{0.f, 0.f, 0.f, 0.f};
    #pragma unroll
    for (int mt = 0; mt < 8; ++mt)
      #pragma unroll
      for (int r = 0; r < 4; ++r) {
        float t = fmaf(gs, acc[mt][q][r], cs);
        float p = exp2f(__builtin_amdgcn_fmed3f(t, 0.f, 80.f));
        sm4[r] += p;
        wb4[r] = fmaf(p, b2f(bcv[mt][r]), wb4[r]);
      }
    smv[q] = (sm4[0] + sm4[1]) + (sm4[2] + sm4[3]);
    wbv[q] = (wb4[0] + wb4[1]) + (wb4[2] + wb4[3]);
  }
  // merge the 4 lane-groups (m-partition): plain adds
  #pragma unroll
  for (int st = 16; st <= 32; st <<= 1) {
    #pragma unroll
    for (int q = 0; q < 2; ++q) {
      smv[q] += __shfl_xor(smv[q], st, 64);
      wbv[q] += __shfl_xor(wbv[q], st, 64);
    }
  }

  __syncthreads();  // all h2s traffic done -> reuse front of smem
  if (lg == 0) {
    #pragma unroll
    for (int q = 0; q < 2; ++q) {
      const int ci = w * 32 + q * 16 + lr;    // local c index in [0,128)
      attL[ci] = A[(size_t)n * 256 + cbase + ci] - wbv[q] / smv[q];
    }
  }
  __syncthreads();

  // ---- fc partial over this block's 128 c -> atomicAdd ----
  {
    const int o = tid >> 4, gp = tid & 15;
    if (o < 13) {
      float s = 0.f;
      #pragma unroll
      for (int i = 0; i < 2; ++i) {
        float4_t av = *(const float4_t*)&attL[gp * 8 + i * 4];
        float4_t wv = *(const float4_t*)&fcw[(size_t)o * 256 + cbase + gp * 8 + i * 4];
        #pragma unroll
        for (int e = 0; e < 4; ++e) s = fmaf(av[e], wv[e], s);
      }
      part[o * 16 + gp] = s;
    }
  }
  __syncthreads();
  if (tid < 13) {
    float s = (cb == 0) ? fcb[tid] : 0.f;
    #pragma unroll
    for (int gp = 0; gp < 16; ++gp) s += part[tid * 16 + gp];
    atomicAdd(&outp[(size_t)n * 13 + tid], s);
  }
}

extern "C" void kernel_launch(void* const* d_in, const int* in_sizes, int n_in,
                              void* d_out, int out_size, void* d_ws, size_t ws_size,
                              hipStream_t stream)
{
  const float* ext = (const float*)d_in[0];
  const float* lab = (const float*)d_in[1];
  const float* w1a = (const float*)d_in[2];
  const float* b1a = (const float*)d_in[3];
  const float* g1a = (const float*)d_in[4];
  const float* be1a= (const float*)d_in[5];
  const float* w1b = (const float*)d_in[6];
  const float* b1b = (const float*)d_in[7];
  const float* g1b = (const float*)d_in[8];
  const float* be1b= (const float*)d_in[9];
  const float* w2a = (const float*)d_in[10];
  const float* b2a = (const float*)d_in[11];
  const float* g2a = (const float*)d_in[12];
  const float* be2a= (const float*)d_in[13];
  const float* w2b = (const float*)d_in[14];
  const float* b2b = (const float*)d_in[15];
  const float* g2b = (const float*)d_in[16];
  const float* be2b= (const float*)d_in[17];
  const float* mw1 = (const float*)d_in[18];
  const float* mb1 = (const float*)d_in[19];
  const float* mg1 = (const float*)d_in[20];
  const float* mbe1= (const float*)d_in[21];
  const float* mw2 = (const float*)d_in[22];
  const float* mb2 = (const float*)d_in[23];
  const float* mg2 = (const float*)d_in[24];
  const float* mbe2= (const float*)d_in[25];
  const float* mw3 = (const float*)d_in[26];
  const float* mb3 = (const float*)d_in[27];
  const float* mg3 = (const float*)d_in[28];
  const float* mbe3= (const float*)d_in[29];
  const float* fcw = (const float*)d_in[30];
  const float* fcb = (const float*)d_in[31];

  char* ws = (char*)d_ws;
  ushort_t* Y1ab = (ushort_t*)(ws);                       // [0,2M) bf16 2048x512 (dead after enc2)
  float*    PA2  = (float*)(ws);                          // [0,256K) written by proj
  float*    PB2  = (float*)(ws + 262144);                 // [256K,272K)
  float*    Aenc = (float*)(ws + (2u << 20));             // [2M,4M) f32 2048x256
  char* b5 = ws + (4u << 20);
  ushort_t* mw2b = (ushort_t*)(b5);                       // 64x32 bf16 (4KB)
  ushort_t* mw3b = (ushort_t*)(b5 + 4096);                // 256x64 bf16 (32KB)
  ushort_t* Y1bb = (ushort_t*)(b5 + 36864);               // 128x512 bf16 (128KB)
  float*    Benc = (float*)(b5 + 167936);                 // 128x256 f32 (128KB)
  ushort_t* BencTb=(ushort_t*)(b5 + 299008);              // 256x128 bf16 (64KB)

  hipMemsetAsync(d_out, 0, (size_t)out_size * sizeof(float), stream);
  enc_mfma<0, 0, 1><<<dim3(68, 8), 256, 0, stream>>>(
      (const void*)ext, (const void*)w1a, b1a, g1a, be1a, (void*)Y1ab,
      (const void*)lab, (const void*)w2a, b2a, g2a, be2a, (void*)Y1bb,
      (ushort_t*)nullptr, 512, 352, 64);
  enc_mfma<1, 0, 0><<<dim3(68, 4), 256, 0, stream>>>(
      (const void*)Y1ab, (const void*)w1b, b1b, g1b, be1b, (void*)Aenc,
      (const void*)Y1bb, (const void*)w2b, b2b, g2b, be2b, (void*)Benc,
      BencTb, 256, 512, 64);
  proj32<<<553, 256, 0, stream>>>(Aenc, Benc, mw1, mb1, mg1, mbe1, PA2, PB2, 512,
                                  mw2, mw3, mw2b, mw3b);
  main_attn<<<dim3(2048, 2), 256, 0, stream>>>(PA2, PB2, Aenc, BencTb,
                                               mw2b, mb2, mg2, mbe2, mw3b, mb3, mg3, mbe3,
                                               fcw, fcb, (float*)d_out);
}